// Round 1
// baseline (442.306 us; speedup 1.0000x reference)
//
#include <hip/hip_runtime.h>
#include <hip/hip_bf16.h>
#include <math.h>

// Problem constants
#define LH 4      // left heads
#define RH 4      // right heads
#define HD 16     // per-head hidden
#define DD 64     // L*H = R*H = 64
#define BB 2
#define TT 96
#define NTOK (BB*TT)           // 192
#define HEADS (LH*RH)          // 16
#define INV_H 0.0625f

// ---------------------------------------------------------------------------
// PartialDense: Y = (Wr^T X Wc + bias) * scale, per token.
// separated=1: scatter into [b, head=(l*4+r), t, row(0..15), col(0..15)]
// separated=0: plain [token, 64, 64]
// ---------------------------------------------------------------------------
__global__ __launch_bounds__(256, 2) void pdense_kernel(
    const float* __restrict__ X, const float* __restrict__ Wr,
    const float* __restrict__ Wc, const float* __restrict__ bias,
    float* __restrict__ dst, float scale, int separated)
{
    __shared__ float Xs[64][64];
    __shared__ float Wcs[64][64];
    __shared__ float Wrs[64][64];
    __shared__ float T1s[64][64];

    const int token = blockIdx.x;
    const int tid = threadIdx.x;
    const float* Xp = X + token * 4096;

    for (int rep = 0; rep < 16; ++rep) {
        int idx = tid + rep * 256;
        ((float*)Xs)[idx]  = Xp[idx];
        ((float*)Wcs)[idx] = Wc[idx];
        ((float*)Wrs)[idx] = Wr[idx];
    }
    __syncthreads();

    // T1 = X @ Wc   (T1[i][b] = sum_j X[i][j] * Wc[j][b])
    for (int rep = 0; rep < 16; ++rep) {
        int idx = tid + rep * 256;
        int i = idx >> 6, b = idx & 63;
        float s = 0.f;
        #pragma unroll
        for (int j = 0; j < 64; ++j) s += Xs[i][j] * Wcs[j][b];
        T1s[i][b] = s;
    }
    __syncthreads();

    // Y = Wr^T @ T1  (Y[a][b] = sum_i Wr[i][a] * T1[i][b])
    for (int rep = 0; rep < 16; ++rep) {
        int idx = tid + rep * 256;
        int a = idx >> 6, b = idx & 63;
        float s = 0.f;
        #pragma unroll
        for (int ii = 0; ii < 64; ++ii) s += Wrs[ii][a] * T1s[ii][b];
        s = (s + bias[idx]) * scale;
        if (separated) {
            int l = a >> 4, p = a & 15, r = b >> 4, c = b & 15;
            int bI = token / TT, t = token % TT;
            dst[(((bI * HEADS + (l * RH + r)) * TT) + t) * 256 + p * 16 + c] = s;
        } else {
            dst[token * 4096 + idx] = s;
        }
    }
}

// ---------------------------------------------------------------------------
// Fused attention per (batch, head, query token).
// Thread (p,u) owns softmax row (i,p,u) over j; accumulates over v[j,u,:].
// Output written in MERGED layout: att[b, i, l*16+p, r*16+u'].
// ---------------------------------------------------------------------------
__global__ __launch_bounds__(256) void attn_kernel(
    const float* __restrict__ q_s, const float* __restrict__ k_s,
    const float* __restrict__ v_s, float* __restrict__ att)
{
    const int blk  = blockIdx.x;
    const int i    = blk % TT;
    const int head = (blk / TT) % HEADS;
    const int bI   = blk / (TT * HEADS);
    const int l = head >> 2, r = head & 3;
    const int tid = threadIdx.x;
    const int p = tid >> 4, u = tid & 15;

    // merged output address for this thread's (p, col=u) element
    float* outp = att + (((bI * TT + i) * DD) + (l * 16 + p)) * DD + r * 16 + u;

    if (r > l) { *outp = 0.f; return; }

    const size_t hb = (size_t)(bI * HEADS + head) * TT * 256;

    // Q row (p, :) of token i -> registers
    const float4* qp = (const float4*)(q_s + hb + (size_t)i * 256 + p * 16);
    float4 q0 = qp[0], q1 = qp[1], q2 = qp[2], q3 = qp[3];

    const float* kbase = k_s + hb + u * 16;
    const float* vbase = v_s + hb + u * 16;

    float mval = -INFINITY, lsum = 0.f;
    float acc[16];
    #pragma unroll
    for (int t = 0; t < 16; ++t) acc[t] = 0.f;

    for (int j = 0; j < TT; ++j) {
        const float4* kr = (const float4*)(kbase + (size_t)j * 256);
        float4 k0 = kr[0], k1 = kr[1], k2 = kr[2], k3 = kr[3];
        float S =
            q0.x*k0.x + q0.y*k0.y + q0.z*k0.z + q0.w*k0.w +
            q1.x*k1.x + q1.y*k1.y + q1.z*k1.z + q1.w*k1.w +
            q2.x*k2.x + q2.y*k2.y + q2.z*k2.z + q2.w*k2.w +
            q3.x*k3.x + q3.y*k3.y + q3.z*k3.z + q3.w*k3.w;
        S *= INV_H;

        if (S > mval) {
            float sc = __expf(mval - S);   // exp(-inf)=0 on first iter
            lsum *= sc;
            #pragma unroll
            for (int t = 0; t < 16; ++t) acc[t] *= sc;
            mval = S;
        }
        float w = __expf(S - mval);
        lsum += w;

        const float4* vr = (const float4*)(vbase + (size_t)j * 256);
        float4 v0 = vr[0], v1 = vr[1], v2 = vr[2], v3 = vr[3];
        acc[0]  += w * v0.x;  acc[1]  += w * v0.y;
        acc[2]  += w * v0.z;  acc[3]  += w * v0.w;
        acc[4]  += w * v1.x;  acc[5]  += w * v1.y;
        acc[6]  += w * v1.z;  acc[7]  += w * v1.w;
        acc[8]  += w * v2.x;  acc[9]  += w * v2.y;
        acc[10] += w * v2.z;  acc[11] += w * v2.w;
        acc[12] += w * v3.x;  acc[13] += w * v3.y;
        acc[14] += w * v3.z;  acc[15] += w * v3.w;
    }

    // normalize this (p,u) row by its own denominator
    float inv = 1.f / lsum;
    #pragma unroll
    for (int t = 0; t < 16; ++t) acc[t] *= inv;

    // reduce over u (16-lane groups): butterfly
    #pragma unroll
    for (int mask = 1; mask < 16; mask <<= 1) {
        #pragma unroll
        for (int t = 0; t < 16; ++t)
            acc[t] += __shfl_xor(acc[t], mask, 16);
    }

    // lane u writes output column u' = u
    *outp = acc[u];
}

// ---------------------------------------------------------------------------
extern "C" void kernel_launch(void* const* d_in, const int* in_sizes, int n_in,
                              void* d_out, int out_size, void* d_ws, size_t ws_size,
                              hipStream_t stream) {
    const float* queries = (const float*)d_in[0];
    const float* keys    = (const float*)d_in[1];
    const float* values  = (const float*)d_in[2];
    const float* Wq_row  = (const float*)d_in[3];
    const float* Wq_col  = (const float*)d_in[4];
    const float* bq      = (const float*)d_in[5];
    const float* Wk_row  = (const float*)d_in[6];
    const float* Wk_col  = (const float*)d_in[7];
    const float* bk      = (const float*)d_in[8];
    const float* Wv_row  = (const float*)d_in[9];
    const float* Wv_col  = (const float*)d_in[10];
    const float* bv      = (const float*)d_in[11];
    const float* Wo_row  = (const float*)d_in[12];
    const float* Wo_col  = (const float*)d_in[13];
    const float* bo      = (const float*)d_in[14];
    float* out = (float*)d_out;

    const size_t SEP = (size_t)BB * HEADS * TT * 256;  // 786432 floats
    float* ws  = (float*)d_ws;
    float* q_s = ws;
    float* k_s = q_s + SEP;
    float* v_s = k_s + SEP;
    float* att = v_s + SEP;

    pdense_kernel<<<NTOK, 256, 0, stream>>>(queries, Wq_row, Wq_col, bq, q_s, INV_H, 1);
    pdense_kernel<<<NTOK, 256, 0, stream>>>(keys,    Wk_row, Wk_col, bk, k_s, INV_H, 1);
    pdense_kernel<<<NTOK, 256, 0, stream>>>(values,  Wv_row, Wv_col, bv, v_s, INV_H, 1);

    attn_kernel<<<BB * HEADS * TT, 256, 0, stream>>>(q_s, k_s, v_s, att);

    pdense_kernel<<<NTOK, 256, 0, stream>>>(att, Wo_row, Wo_col, bo, out, INV_H, 0);
}

// Round 2
// 187.193 us; speedup vs baseline: 2.3628x; 2.3628x over previous
//
#include <hip/hip_runtime.h>
#include <hip/hip_bf16.h>
#include <math.h>

// Problem constants
#define LH 4      // left heads
#define RH 4      // right heads
#define HD 16     // per-head hidden
#define DD 64     // L*H = R*H = 64
#define BB 2
#define TT 96
#define NTOK (BB*TT)           // 192
#define HEADS (LH*RH)          // 16
#define INV_H 0.0625f
#define NQ 4                   // queries per block (per thread)
#define QCHUNKS (TT/NQ)        // 24
#define VHEADS 10              // heads with r <= l

// ---------------------------------------------------------------------------
// PartialDense: Y = (Wr^T X Wc + bias) * scale, per token.
// separated=1: scatter into [b, head=(l*4+r), t, row(0..15), col(0..15)]
// separated=0: plain [token, 64, 64]
// ---------------------------------------------------------------------------
__global__ __launch_bounds__(256, 2) void pdense_kernel(
    const float* __restrict__ X, const float* __restrict__ Wr,
    const float* __restrict__ Wc, const float* __restrict__ bias,
    float* __restrict__ dst, float scale, int separated)
{
    __shared__ float Xs[64][64];
    __shared__ float Wcs[64][64];
    __shared__ float Wrs[64][64];
    __shared__ float T1s[64][64];

    const int token = blockIdx.x;
    const int tid = threadIdx.x;
    const float* Xp = X + token * 4096;

    for (int rep = 0; rep < 16; ++rep) {
        int idx = tid + rep * 256;
        ((float*)Xs)[idx]  = Xp[idx];
        ((float*)Wcs)[idx] = Wc[idx];
        ((float*)Wrs)[idx] = Wr[idx];
    }
    __syncthreads();

    // T1 = X @ Wc
    for (int rep = 0; rep < 16; ++rep) {
        int idx = tid + rep * 256;
        int i = idx >> 6, b = idx & 63;
        float s = 0.f;
        #pragma unroll
        for (int j = 0; j < 64; ++j) s += Xs[i][j] * Wcs[j][b];
        T1s[i][b] = s;
    }
    __syncthreads();

    // Y = Wr^T @ T1
    for (int rep = 0; rep < 16; ++rep) {
        int idx = tid + rep * 256;
        int a = idx >> 6, b = idx & 63;
        float s = 0.f;
        #pragma unroll
        for (int ii = 0; ii < 64; ++ii) s += Wrs[ii][a] * T1s[ii][b];
        s = (s + bias[idx]) * scale;
        if (separated) {
            int l = a >> 4, p = a & 15, r = b >> 4, c = b & 15;
            int bI = token / TT, t = token % TT;
            dst[(((bI * HEADS + (l * RH + r)) * TT) + t) * 256 + p * 16 + c] = s;
        } else {
            dst[token * 4096 + idx] = s;
        }
    }
}

// ---------------------------------------------------------------------------
__global__ __launch_bounds__(256) void zerofill_kernel(float4* __restrict__ p)
{
    p[blockIdx.x * 256 + threadIdx.x] = float4{0.f, 0.f, 0.f, 0.f};
}

// ---------------------------------------------------------------------------
// Fused attention. Block = (batch, valid head, chunk of NQ query tokens).
// Thread (p,u) owns softmax rows (i0..i0+3, p, u) over j.
// No max subtraction: logits are tiny (|S| << 1), exp(S) is safe in fp32.
// ---------------------------------------------------------------------------
__global__ __launch_bounds__(256, 2) void attn_kernel(
    const float* __restrict__ q_s, const float* __restrict__ k_s,
    const float* __restrict__ v_s, float* __restrict__ att)
{
    const int qc = blockIdx.x % QCHUNKS;
    const int vh = (blockIdx.x / QCHUNKS) % VHEADS;
    const int bI = blockIdx.x / (QCHUNKS * VHEADS);
    // vh -> (l, r) with r <= l
    const int l = (vh >= 1) + (vh >= 3) + (vh >= 6);
    const int r = vh - (l * (l + 1)) / 2;
    const int head = l * RH + r;
    const int i0 = qc * NQ;
    const int tid = threadIdx.x;
    const int p = tid >> 4, u = tid & 15;

    const size_t hb = (size_t)(bI * HEADS + head) * TT * 256;

    // Q rows (p,:) for NQ query tokens
    float4 q[NQ][4];
    #pragma unroll
    for (int qi = 0; qi < NQ; ++qi) {
        const float4* qp = (const float4*)(q_s + hb + (size_t)(i0 + qi) * 256 + p * 16);
        q[qi][0] = qp[0]; q[qi][1] = qp[1]; q[qi][2] = qp[2]; q[qi][3] = qp[3];
    }

    const float* kb = k_s + hb + u * 16;
    const float* vb = v_s + hb + u * 16;

    float lsum[NQ];
    float acc[NQ][16];
    #pragma unroll
    for (int qi = 0; qi < NQ; ++qi) {
        lsum[qi] = 0.f;
        #pragma unroll
        for (int t = 0; t < 16; ++t) acc[qi][t] = 0.f;
    }

    #pragma unroll 2
    for (int j = 0; j < TT; ++j) {
        const float4* kr = (const float4*)(kb + (size_t)j * 256);
        float4 k0 = kr[0], k1 = kr[1], k2 = kr[2], k3 = kr[3];
        const float4* vr = (const float4*)(vb + (size_t)j * 256);
        float4 v0 = vr[0], v1 = vr[1], v2 = vr[2], v3 = vr[3];

        #pragma unroll
        for (int qi = 0; qi < NQ; ++qi) {
            float S =
                q[qi][0].x*k0.x + q[qi][0].y*k0.y + q[qi][0].z*k0.z + q[qi][0].w*k0.w +
                q[qi][1].x*k1.x + q[qi][1].y*k1.y + q[qi][1].z*k1.z + q[qi][1].w*k1.w +
                q[qi][2].x*k2.x + q[qi][2].y*k2.y + q[qi][2].z*k2.z + q[qi][2].w*k2.w +
                q[qi][3].x*k3.x + q[qi][3].y*k3.y + q[qi][3].z*k3.z + q[qi][3].w*k3.w;
            float w = __expf(S * INV_H);
            lsum[qi] += w;
            acc[qi][0]  += w * v0.x;  acc[qi][1]  += w * v0.y;
            acc[qi][2]  += w * v0.z;  acc[qi][3]  += w * v0.w;
            acc[qi][4]  += w * v1.x;  acc[qi][5]  += w * v1.y;
            acc[qi][6]  += w * v1.z;  acc[qi][7]  += w * v1.w;
            acc[qi][8]  += w * v2.x;  acc[qi][9]  += w * v2.y;
            acc[qi][10] += w * v2.z;  acc[qi][11] += w * v2.w;
            acc[qi][12] += w * v3.x;  acc[qi][13] += w * v3.y;
            acc[qi][14] += w * v3.z;  acc[qi][15] += w * v3.w;
        }
    }

    #pragma unroll
    for (int qi = 0; qi < NQ; ++qi) {
        float inv = 1.f / lsum[qi];
        #pragma unroll
        for (int t = 0; t < 16; ++t) acc[qi][t] *= inv;

        // reduce over u (16-lane groups)
        #pragma unroll
        for (int mask = 1; mask < 16; mask <<= 1) {
            #pragma unroll
            for (int t = 0; t < 16; ++t)
                acc[qi][t] += __shfl_xor(acc[qi][t], mask, 16);
        }

        // lane u writes output column u; static-index select (avoid scratch)
        float outv = acc[qi][0];
        #pragma unroll
        for (int t = 1; t < 16; ++t)
            outv = (u == t) ? acc[qi][t] : outv;

        att[(((size_t)(bI * TT + i0 + qi) * DD) + (l * 16 + p)) * DD + r * 16 + u] = outv;
    }
}

// ---------------------------------------------------------------------------
extern "C" void kernel_launch(void* const* d_in, const int* in_sizes, int n_in,
                              void* d_out, int out_size, void* d_ws, size_t ws_size,
                              hipStream_t stream) {
    const float* queries = (const float*)d_in[0];
    const float* keys    = (const float*)d_in[1];
    const float* values  = (const float*)d_in[2];
    const float* Wq_row  = (const float*)d_in[3];
    const float* Wq_col  = (const float*)d_in[4];
    const float* bq      = (const float*)d_in[5];
    const float* Wk_row  = (const float*)d_in[6];
    const float* Wk_col  = (const float*)d_in[7];
    const float* bk      = (const float*)d_in[8];
    const float* Wv_row  = (const float*)d_in[9];
    const float* Wv_col  = (const float*)d_in[10];
    const float* bv      = (const float*)d_in[11];
    const float* Wo_row  = (const float*)d_in[12];
    const float* Wo_col  = (const float*)d_in[13];
    const float* bo      = (const float*)d_in[14];
    float* out = (float*)d_out;

    const size_t SEP = (size_t)BB * HEADS * TT * 256;  // 786432 floats
    float* ws  = (float*)d_ws;
    float* q_s = ws;
    float* k_s = q_s + SEP;
    float* v_s = k_s + SEP;
    float* att = v_s + SEP;

    pdense_kernel<<<NTOK, 256, 0, stream>>>(queries, Wq_row, Wq_col, bq, q_s, INV_H, 1);
    pdense_kernel<<<NTOK, 256, 0, stream>>>(keys,    Wk_row, Wk_col, bk, k_s, INV_H, 1);
    pdense_kernel<<<NTOK, 256, 0, stream>>>(values,  Wv_row, Wv_col, bv, v_s, INV_H, 1);

    // zero the attention output buffer (covers the r>l masked head blocks)
    zerofill_kernel<<<(BB * TT * DD * DD) / (256 * 4), 256, 0, stream>>>((float4*)att);

    attn_kernel<<<BB * VHEADS * QCHUNKS, 256, 0, stream>>>(q_s, k_s, v_s, att);

    pdense_kernel<<<NTOK, 256, 0, stream>>>(att, Wo_row, Wo_col, bo, out, INV_H, 0);
}